// Round 1
// baseline (276.482 us; speedup 1.0000x reference)
//
#include <hip/hip_runtime.h>

#define THREADS 192
#define RB 12              // output rows per block
#define IN_ROWS (RB + 4)   // 16 input rows staged
#define ROWSTRIDE 68       // 64 + 4 pad floats, breaks LDS bank aliasing
#define NG 15              // 60/4 column groups

// inverse connectivity: for each input channel, the 10 output maps it feeds
__device__ constexpr int CONN_INV[6][10] = {
    {0, 4, 5, 6, 9, 10, 11, 12, 14, 15},
    {0, 1, 5, 6, 7, 10, 11, 12, 13, 15},
    {0, 1, 2, 6, 7, 8, 11, 13, 14, 15},
    {1, 2, 3, 6, 7, 8, 9, 12, 14, 15},
    {2, 3, 4, 7, 8, 9, 10, 12, 13, 15},
    {3, 4, 5, 8, 9, 10, 11, 13, 14, 15},
};

__global__ __launch_bounds__(THREADS, 4)
void c3_conv(const float* __restrict__ x, const float* __restrict__ W,
             const float* __restrict__ bias, float* __restrict__ out) {
    __shared__ float xs[6 * IN_ROWS * ROWSTRIDE];

    const int blk  = blockIdx.x;
    const int img  = blk / 5;
    const int band = blk - img * 5;
    const int r0   = band * RB;
    const int t    = threadIdx.x;

    // ---- stage input tile: 6 channels x 16 rows x 64 cols (f32) ----
    // global: contiguous per channel; LDS: row stride 68 floats.
    const float4* src = reinterpret_cast<const float4*>(x) + (size_t)img * (6 * 64 * 16);
    float4* dst = reinterpret_cast<float4*>(xs);
    #pragma unroll
    for (int k = 0; k < 8; ++k) {
        int s   = t + k * THREADS;      // 0..1535
        int ic  = s >> 8;               // /256 (256 float4 per channel tile)
        int rem = s & 255;
        int iy  = rem >> 4;             // row within tile
        int c4  = rem & 15;             // float4 within row
        dst[(ic * IN_ROWS + iy) * (ROWSTRIDE / 4) + c4] =
            src[ic * 1024 + (r0 + iy) * 16 + c4];
    }
    __syncthreads();

    if (t < RB * NG) {                  // 180 active threads
        const int row = t / NG;         // 0..11
        const int g   = t - row * NG;   // 0..14
        const int c0  = g * 4;

        float acc[16][4];
        #pragma unroll
        for (int oc = 0; oc < 16; ++oc) {
            float bv = bias[oc];        // uniform -> s_load
            #pragma unroll
            for (int j = 0; j < 4; ++j) acc[oc][j] = bv;
        }

        for (int ky = 0; ky < 5; ++ky) {
            #pragma unroll
            for (int ic = 0; ic < 6; ++ic) {
                const float* xr = xs + (ic * IN_ROWS + row + ky) * ROWSTRIDE + c0;
                float xv[8];
                *reinterpret_cast<float4*>(&xv[0]) = *reinterpret_cast<const float4*>(&xr[0]);
                *reinterpret_cast<float4*>(&xv[4]) = *reinterpret_cast<const float4*>(&xr[4]);
                #pragma unroll
                for (int u = 0; u < 10; ++u) {
                    const int oc = CONN_INV[ic][u];
                    const float* wp = W + (((oc * 6 + ic) * 5 + ky) * 5);  // uniform -> s_load
                    #pragma unroll
                    for (int kx = 0; kx < 5; ++kx) {
                        const float w = wp[kx];
                        #pragma unroll
                        for (int j = 0; j < 4; ++j)
                            acc[oc][j] = fmaf(xv[kx + j], w, acc[oc][j]);
                    }
                }
            }
        }

        // ---- store: out[img][oc][r0+row][c0..c0+3], 16B aligned ----
        float* op = out + (size_t)img * 57600 + (size_t)(r0 + row) * 60 + c0;
        #pragma unroll
        for (int oc = 0; oc < 16; ++oc) {
            float4 v = make_float4(acc[oc][0], acc[oc][1], acc[oc][2], acc[oc][3]);
            *reinterpret_cast<float4*>(op + oc * 3600) = v;
        }
    }
}

extern "C" void kernel_launch(void* const* d_in, const int* in_sizes, int n_in,
                              void* d_out, int out_size, void* d_ws, size_t ws_size,
                              hipStream_t stream) {
    const float* x  = (const float*)d_in[0];
    const float* W  = (const float*)d_in[1];
    const float* b  = (const float*)d_in[2];
    float* out      = (float*)d_out;

    const int nimg = in_sizes[0] / (6 * 64 * 64);   // 2048
    dim3 grid(nimg * 5), block(THREADS);
    hipLaunchKernelGGL(c3_conv, grid, block, 0, stream, x, W, b, out);
}